// Round 20
// baseline (248.274 us; speedup 1.0000x reference)
//
#include <hip/hip_runtime.h>
#include <hip/hip_fp16.h>

#define NN 100000      // nodes
#define NE 1600000     // edges
#define INC 128        // in channels
#define HID 96         // hidden
#define NG 512         // graphs

#define GEMM1_BLOCKS 1563        // ceil(NN/64)

#define BK_SHIFT 8
#define BK_SIZE 256
#define NBK 391                  // ceil(NN/256)
#define A_EPB 4096               // edges per A-pass block
#define A_BLOCKS 391             // ceil(NE/4096)

typedef _Float16 half8 __attribute__((ext_vector_type(8)));
typedef float f32x4 __attribute__((ext_vector_type(4)));

// ---------------- FUSED: A1 (per-block bucket histogram) ∥ W1frag + W2h pack ----------------
__global__ __launch_bounds__(256) void k_pack_a1(const int* __restrict__ dst,
                                                 int* __restrict__ histAB,
                                                 const float* __restrict__ W1,
                                                 const float* __restrict__ W2,
                                                 __half* __restrict__ W1frag,
                                                 __half* __restrict__ W2h) {
    const int tid = threadIdx.x;
    if (blockIdx.x < A_BLOCKS) {
        __shared__ int cnt[NBK];
        int ab = blockIdx.x;
        for (int i = tid; i < NBK; i += 256) cnt[i] = 0;
        __syncthreads();
        int e0 = ab * A_EPB;
#pragma unroll 4
        for (int q = 0; q < A_EPB / 256; ++q) {
            int e = e0 + q * 256 + tid;
            if (e < NE) atomicAdd(&cnt[dst[e] >> BK_SHIFT], 1);
        }
        __syncthreads();
        for (int i = tid; i < NBK; i += 256) histAB[ab * NBK + i] = cnt[i];
        return;
    }
    int p = (blockIdx.x - A_BLOCKS) * 256 + tid;
    if (p < 1536) {
        // ---- W1 fragment pack (MFMA gemm1) ----
        int kc = p / 384;
        int rem = p - kc * 384;
        int ct = rem >> 6;
        int l = rem & 63;
#pragma unroll
        for (int i = 0; i < 8; ++i) {
            int k = kc * 32 + ((l >> 4) << 3) + i;
            int c = ct * 16 + (l & 15);
            W1frag[p * 8 + i] = __float2half(W1[k * HID + c]);
        }
    } else {
        int q = p - 1536;
        if (q >= 1152) return;
        // ---- W2 plain fp16 pack (row-major, consumed in agg2 epilogue) ----
#pragma unroll
        for (int i = 0; i < 8; ++i) W2h[q * 8 + i] = __float2half(W2[q * 8 + i]);
    }
}

// ---------------- scanS: column prefix of histAB + bucket prefix -> boff ----------------
__global__ __launch_bounds__(512) void k_scanS(int* __restrict__ histAB, int* __restrict__ boff) {
    __shared__ int tot[512];
    int t = threadIdx.x;
    int run = 0;
    if (t < NBK) {
        for (int blk = 0; blk < A_BLOCKS; ++blk) {
            int idx = blk * NBK + t;
            int v = histAB[idx];
            histAB[idx] = run;
            run += v;
        }
    }
    tot[t] = (t < NBK) ? run : 0;
    __syncthreads();
    for (int ofs = 1; ofs < 512; ofs <<= 1) {
        int v = (t >= ofs) ? tot[t - ofs] : 0;
        __syncthreads();
        tot[t] += v;
        __syncthreads();
    }
    if (t == 0) boff[0] = 0;
    if (t < NBK) boff[t + 1] = tot[t];
}

// ---------------- FUSED: A3 (binned edge write) ∥ gemm1 (MFMA fp16) ----------------
__global__ __launch_bounds__(256) void k_gemm1_a3(
        const float* __restrict__ X, const __half* __restrict__ W1frag,
        __half* __restrict__ Yh,
        const int* __restrict__ src, const int* __restrict__ dst,
        const int* __restrict__ boff, const int* __restrict__ histAB,
        unsigned* __restrict__ tmp) {
    __shared__ __half w1s[12288];
    const int tid = threadIdx.x;

    if (blockIdx.x < A_BLOCKS) {
        int* base = (int*)w1s;
        int* lcnt = base + NBK;
        int ab = blockIdx.x;
        for (int i = tid; i < NBK; i += 256) {
            base[i] = boff[i] + histAB[ab * NBK + i];
            lcnt[i] = 0;
        }
        __syncthreads();
        int e0 = ab * A_EPB;
#pragma unroll 4
        for (int q = 0; q < A_EPB / 256; ++q) {
            int e = e0 + q * 256 + tid;
            if (e < NE) {
                int d = dst[e];
                int bk = d >> BK_SHIFT;
                int lp = atomicAdd(&lcnt[bk], 1);
                tmp[base[bk] + lp] = (unsigned)src[e] | ((unsigned)(d & (BK_SIZE - 1)) << 17);
            }
        }
        return;
    }

    // ---- gemm1 MFMA body (K = 128, 4 steps) ----
    {
        half8* d8 = (half8*)w1s;
        const half8* s8 = (const half8*)W1frag;
        for (int i = tid; i < 1536; i += 256) d8[i] = s8[i];
    }
    __syncthreads();
    const int w = tid >> 6;
    const int l = tid & 63;
    const int row0 = (blockIdx.x - A_BLOCKS) * 64 + w * 16;
    int arow = row0 + (l & 15);
    if (arow >= NN) arow = NN - 1;
    f32x4 acc[6] = {};
#pragma unroll
    for (int kc = 0; kc < 4; ++kc) {
        const float* xp = &X[(size_t)arow * INC + kc * 32 + ((l >> 4) << 3)];
        float4 xa = *(const float4*)xp;
        float4 xb = *(const float4*)(xp + 4);
        half8 a;
        a[0] = (_Float16)xa.x; a[1] = (_Float16)xa.y;
        a[2] = (_Float16)xa.z; a[3] = (_Float16)xa.w;
        a[4] = (_Float16)xb.x; a[5] = (_Float16)xb.y;
        a[6] = (_Float16)xb.z; a[7] = (_Float16)xb.w;
#pragma unroll
        for (int ct = 0; ct < 6; ++ct) {
            half8 b = *(const half8*)&w1s[((kc * 6 + ct) * 64 + l) * 8];
            acc[ct] = __builtin_amdgcn_mfma_f32_16x16x32_f16(a, b, acc[ct], 0, 0, 0);
        }
    }
    const int orow = row0 + ((l >> 4) << 2);
    const int col = l & 15;
#pragma unroll
    for (int ct = 0; ct < 6; ++ct)
#pragma unroll
        for (int i = 0; i < 4; ++i) {
            int r = orow + i;
            if (r < NN) Yh[(size_t)r * HID + ct * 16 + col] = __float2half(acc[ct][i]);
        }
}

// ---------------- B1: per-bucket degree count -> off (+dis); 1 node/thread ----------------
__global__ __launch_bounds__(256) void k_B1(const unsigned* __restrict__ tmp,
                                            const int* __restrict__ boff,
                                            int* __restrict__ off, float* __restrict__ dis) {
    __shared__ int cnt[BK_SIZE];
    __shared__ int psum[256];
    const int t = threadIdx.x;
    const int b = blockIdx.x;
    const int nb = b << BK_SHIFT;
    const int rbeg = boff[b], rend = boff[b + 1];
    cnt[t] = 0;
    __syncthreads();
    for (int e = rbeg + t; e < rend; e += 256) {
        unsigned u = tmp[e];
        atomicAdd(&cnt[u >> 17], 1);
    }
    __syncthreads();
    int c = cnt[t];
    psum[t] = c;
    __syncthreads();
    for (int ofs = 1; ofs < 256; ofs <<= 1) {
        int v = (t >= ofs) ? psum[t - ofs] : 0;
        __syncthreads();
        psum[t] += v;
        __syncthreads();
    }
    int node = nb + t;
    if (node < NN) {
        off[node] = rbeg + psum[t] - c;
        dis[node] = rsqrtf((float)(c + 1));
    }
    if (b == NBK - 1 && t == 0) off[NN] = rend;
}

// ---------------- B2: per-bucket scatter into final CSR {src, w} ----------------
__global__ __launch_bounds__(256) void k_B2(const unsigned* __restrict__ tmp,
                                            const int* __restrict__ boff,
                                            const int* __restrict__ off,
                                            const float* __restrict__ dis,
                                            int2* __restrict__ ssrcw) {
    __shared__ int cnt[BK_SIZE];
    const int t = threadIdx.x;
    const int b = blockIdx.x;
    const int nb = b << BK_SHIFT;
    const int rbeg = boff[b], rend = boff[b + 1];
    cnt[t] = 0;
    __syncthreads();
    for (int e = rbeg + t; e < rend; e += 256) {
        unsigned u = tmp[e];
        int s = (int)(u & 0x1FFFFu);
        int dl = (int)(u >> 17);
        int d = nb + dl;
        int pos = off[d] + atomicAdd(&cnt[dl], 1);
        float w = dis[s] * dis[d];
        ssrcw[pos] = make_int2(s, __float_as_int(w));
    }
}

// ---------------- agg batch helper: B edges, int2 descriptors ----------------
template <int B>
__device__ __forceinline__ void agg_batch(const __half* __restrict__ Ah,
                                          const int2* __restrict__ ssrcw, int j, int t,
                                          float& a0x, float& a0y, float& a1x, float& a1y,
                                          float& a2x, float& a2y) {
    int2 e[B];
#pragma unroll
    for (int q = 0; q < B; ++q) e[q] = ssrcw[j + q];
    float w[B];
    const __half2* ap[B];
#pragma unroll
    for (int q = 0; q < B; ++q) {
        w[q] = __int_as_float(e[q].y);
        ap[q] = (const __half2*)(Ah + (size_t)e[q].x * HID);
    }
    __half2 g0[B], g1[B], g2[B];
#pragma unroll
    for (int q = 0; q < B; ++q) {
        g0[q] = ap[q][t];
        g1[q] = ap[q][t + 16];
        g2[q] = ap[q][t + 32];
    }
#pragma unroll
    for (int q = 0; q < B; ++q) {
        float2 f0 = __half22float2(g0[q]);
        float2 f1 = __half22float2(g1[q]);
        float2 f2 = __half22float2(g2[q]);
        a0x += f0.x * w[q]; a0y += f0.y * w[q];
        a1x += f1.x * w[q]; a1y += f1.y * w[q];
        a2x += f2.x * w[q]; a2y += f2.y * w[q];
    }
}

// ---------------- fused GCN aggregation + node-logit partial (16 lanes/dst, half2) ------
// PHASE 1: H1 = relu(agg(Ah)+b1)                    ; nodeOut = bn + h1.Wn[:96]
// PHASE 2: M = agg(H1h); H2 = relu(M@W2h + b2)      ; nodeOut += h2.Wn[96:]
//          (gemm2 commuted into the epilogue: agg(H1@W2) == agg(H1)@W2)
template <int PHASE>
__global__ __launch_bounds__(256) void k_agg(const __half* __restrict__ Ah,
                                             const int2* __restrict__ ssrcw,
                                             const int* __restrict__ off,
                                             const float* __restrict__ dis,
                                             const float* __restrict__ bias,
                                             const float* __restrict__ Wn,
                                             const float* __restrict__ bn,
                                             const __half* __restrict__ W2h,
                                             __half* __restrict__ outh,
                                             float* __restrict__ nodeOut) {
    extern __shared__ char smem[];   // PHASE2: [18432B W2 fp16][16*100 f32 M rows]
    int gid = blockIdx.x * blockDim.x + threadIdx.x;
    int d = gid >> 4;
    int t = gid & 15;

    if (PHASE == 2) {
        // stage W2 into LDS (no barrier yet; barrier comes before epilogue reads)
        half8* d8 = (half8*)smem;
        const half8* s8 = (const half8*)W2h;
        for (int i = threadIdx.x; i < 1152; i += 256) d8[i] = s8[i];
    }
    if (d >= NN) return;   // never taken: NN*16 % 256 == 0

    const int beg = off[d], end = off[d + 1];
    const float dd = dis[d];
    const __half2* ad2 = (const __half2*)(Ah + (size_t)d * HID);
    float2 s0 = __half22float2(ad2[t]);
    float2 s1 = __half22float2(ad2[t + 16]);
    float2 s2 = __half22float2(ad2[t + 32]);
    const float dd2 = dd * dd;
    float a0x = s0.x * dd2, a0y = s0.y * dd2;
    float a1x = s1.x * dd2, a1y = s1.y * dd2;
    float a2x = s2.x * dd2, a2y = s2.y * dd2;
    int j = beg;
    for (; j + 11 < end; j += 12)
        agg_batch<12>(Ah, ssrcw, j, t, a0x, a0y, a1x, a1y, a2x, a2y);
    for (; j + 3 < end; j += 4)
        agg_batch<4>(Ah, ssrcw, j, t, a0x, a0y, a1x, a1y, a2x, a2y);
    for (; j < end; ++j) {
        int2 e0 = ssrcw[j];
        float w0 = __int_as_float(e0.y);
        const __half2* a0 = (const __half2*)(Ah + (size_t)e0.x * HID);
        float2 f0 = __half22float2(a0[t]);
        float2 f1 = __half22float2(a0[t + 16]);
        float2 f2 = __half22float2(a0[t + 32]);
        a0x += f0.x * w0; a0y += f0.y * w0;
        a1x += f1.x * w0; a1y += f1.y * w0;
        a2x += f2.x * w0; a2y += f2.y * w0;
    }

    if (PHASE == 1) {
        const float2* b2p = (const float2*)bias;
        float2 b0 = b2p[t], b1 = b2p[t + 16], b2 = b2p[t + 32];
        float h0x = fmaxf(a0x + b0.x, 0.f), h0y = fmaxf(a0y + b0.y, 0.f);
        float h1x = fmaxf(a1x + b1.x, 0.f), h1y = fmaxf(a1y + b1.y, 0.f);
        float h2x = fmaxf(a2x + b2.x, 0.f), h2y = fmaxf(a2y + b2.y, 0.f);
        __half2* o2 = (__half2*)(outh + (size_t)d * HID);
        o2[t]      = __floats2half2_rn(h0x, h0y);
        o2[t + 16] = __floats2half2_rn(h1x, h1y);
        o2[t + 32] = __floats2half2_rn(h2x, h2y);
        const float2* wn2 = (const float2*)Wn;
        float2 w0v = wn2[t], w1v = wn2[t + 16], w2v = wn2[t + 32];
        float partial = h0x * w0v.x + h0y * w0v.y + h1x * w1v.x + h1y * w1v.y +
                        h2x * w2v.x + h2y * w2v.y;
#pragma unroll
        for (int m = 8; m; m >>= 1) partial += __shfl_down(partial, m, 16);
        if (t == 0) nodeOut[d] = partial + bn[0];
    } else {
        // ---- epilogue: y = M @ W2 (LDS), h2 = relu(y + b2); lane t owns cols 6t..6t+5 ----
        float* Mg = (float*)(smem + 18432) + (threadIdx.x >> 4) * 100;
        Mg[2 * t] = a0x;      Mg[2 * t + 1] = a0y;
        Mg[32 + 2 * t] = a1x; Mg[33 + 2 * t] = a1y;
        Mg[64 + 2 * t] = a2x; Mg[65 + 2 * t] = a2y;
        __syncthreads();
        const __half2* w2s2 = (const __half2*)smem;   // [96][48] half2
        float y0x = 0, y0y = 0, y1x = 0, y1y = 0, y2x = 0, y2y = 0;
#pragma unroll 8
        for (int k = 0; k < 96; ++k) {
            float m = Mg[k];
            __half2 wa = w2s2[k * 48 + 3 * t];
            __half2 wb = w2s2[k * 48 + 3 * t + 1];
            __half2 wc = w2s2[k * 48 + 3 * t + 2];
            float2 fa = __half22float2(wa), fb = __half22float2(wb), fc = __half22float2(wc);
            y0x += m * fa.x; y0y += m * fa.y;
            y1x += m * fb.x; y1y += m * fb.y;
            y2x += m * fc.x; y2y += m * fc.y;
        }
        const float2* b2p = (const float2*)bias;
        float2 B0 = b2p[3 * t], B1 = b2p[3 * t + 1], B2v = b2p[3 * t + 2];
        float h0x = fmaxf(y0x + B0.x, 0.f), h0y = fmaxf(y0y + B0.y, 0.f);
        float h1x = fmaxf(y1x + B1.x, 0.f), h1y = fmaxf(y1y + B1.y, 0.f);
        float h2x = fmaxf(y2x + B2v.x, 0.f), h2y = fmaxf(y2y + B2v.y, 0.f);
        __half2* o2 = (__half2*)(outh + (size_t)d * HID);
        o2[3 * t]     = __floats2half2_rn(h0x, h0y);
        o2[3 * t + 1] = __floats2half2_rn(h1x, h1y);
        o2[3 * t + 2] = __floats2half2_rn(h2x, h2y);
        const float2* wn2 = (const float2*)(Wn + 96);
        float2 w0v = wn2[3 * t], w1v = wn2[3 * t + 1], w2v = wn2[3 * t + 2];
        float partial = h0x * w0v.x + h0y * w0v.y + h1x * w1v.x + h1y * w1v.y +
                        h2x * w2v.x + h2y * w2v.y;
#pragma unroll
        for (int m = 8; m; m >>= 1) partial += __shfl_down(partial, m, 16);
        if (t == 0) nodeOut[d] += partial;
    }
}

// ---------------- graph pooling + graph head (fp16 H inputs, 2x node unroll) ----------------
__global__ __launch_bounds__(768) void k_pool(const __half* __restrict__ h1,
                                              const __half* __restrict__ h2,
                                              const int* __restrict__ batch,
                                              const float* __restrict__ Wg,
                                              const float* __restrict__ bg,
                                              float* __restrict__ out) {
    int g = blockIdx.x;
    int tid = threadIdx.x;       // 0..767
    int way = tid / 192;         // 0..3
    int f = tid - way * 192;     // 0..191

    int lo = 0, hi = NN;
    while (lo < hi) { int mid = (lo + hi) >> 1; if (batch[mid] < g) lo = mid + 1; else hi = mid; }
    int start = lo;
    hi = NN;
    while (lo < hi) { int mid = (lo + hi) >> 1; if (batch[mid] < g + 1) lo = mid + 1; else hi = mid; }
    int end = lo;

    const __half* hsrc = (f < HID) ? h1 : h2;
    int ff = (f < HID) ? f : f - HID;
    float sum = 0.f, mx = 0.f;  // h >= 0 post-relu
    int n = start + way;
    for (; n + 4 < end; n += 8) {
        float v0 = __half2float(hsrc[(size_t)n * HID + ff]);
        float v1 = __half2float(hsrc[(size_t)(n + 4) * HID + ff]);
        sum += v0 + v1;
        mx = fmaxf(mx, fmaxf(v0, v1));
    }
    if (n < end) {
        float v0 = __half2float(hsrc[(size_t)n * HID + ff]);
        sum += v0;
        mx = fmaxf(mx, v0);
    }
    __shared__ float rsum[4][192];
    __shared__ float rmax[4][192];
    rsum[way][f] = sum;
    rmax[way][f] = mx;
    __syncthreads();
    if (way == 0) {
        sum = rsum[0][f] + rsum[1][f] + rsum[2][f] + rsum[3][f];
        mx = fmaxf(fmaxf(rmax[0][f], rmax[1][f]), fmaxf(rmax[2][f], rmax[3][f]));
        float cnt = (float)(end - start);
        float mean = sum / fmaxf(cnt, 1.0f);
        rsum[0][f] = mean * Wg[f] + mx * Wg[192 + f];
    }
    __syncthreads();
    if (tid < 64) {
        float acc = rsum[0][tid] + rsum[0][tid + 64] + rsum[0][tid + 128];
#pragma unroll
        for (int m = 32; m; m >>= 1) acc += __shfl_down(acc, m, 64);
        if (tid == 0) out[g] = acc + bg[0];
    }
}

extern "C" void kernel_launch(void* const* d_in, const int* in_sizes, int n_in,
                              void* d_out, int out_size, void* d_ws, size_t ws_size,
                              hipStream_t stream) {
    const float* x    = (const float*)d_in[0];
    const int*   ei   = (const int*)d_in[1];
    const int*   srcp = ei;
    const int*   dstp = ei + NE;
    const int*   batch = (const int*)d_in[2];
    const float* W1 = (const float*)d_in[3];
    const float* b1 = (const float*)d_in[4];
    const float* W2 = (const float*)d_in[5];
    const float* b2 = (const float*)d_in[6];
    const float* Wn = (const float*)d_in[7];
    const float* bn = (const float*)d_in[8];
    const float* Wg = (const float*)d_in[9];
    const float* bg = (const float*)d_in[10];
    float* out = (float*)d_out;

    char* p = (char*)d_ws;
    auto alloc = [&](size_t bytes) {
        char* r = p;
        p += (bytes + 255) & ~(size_t)255;
        return (void*)r;
    };
    float*    dis    = (float*)alloc(NN * 4);
    int*      off    = (int*)alloc((NN + 1) * 4);
    int*      boff   = (int*)alloc((NBK + 1) * 4);
    int*      histAB = (int*)alloc((size_t)A_BLOCKS * NBK * 4);
    unsigned* tmp    = (unsigned*)alloc((size_t)NE * 4);
    int2*     ssrcw  = (int2*)alloc((size_t)NE * 8);
    __half*   Ah     = (__half*)alloc((size_t)NN * HID * 2);   // gemm1 output (conv1 agg src)
    __half*   H1h    = (__half*)alloc((size_t)NN * HID * 2);
    __half*   H2h    = (__half*)alloc((size_t)NN * HID * 2);
    __half*   W1frag = (__half*)alloc(12288 * 2);
    __half*   W2h    = (__half*)alloc(9216 * 2);

    const int TPB = 256;

    // CSR build + weight pack: [A1 ∥ pack] ; scanS ; [A3 ∥ gemm1-MFMA] ; B1 ; B2
    k_pack_a1<<<A_BLOCKS + 11, TPB, 0, stream>>>(dstp, histAB, W1, W2, W1frag, W2h);
    k_scanS<<<1, 512, 0, stream>>>(histAB, boff);
    k_gemm1_a3<<<A_BLOCKS + GEMM1_BLOCKS, 256, 0, stream>>>(
        x, W1frag, Ah, srcp, dstp, boff, histAB, tmp);
    k_B1<<<NBK, 256, 0, stream>>>(tmp, boff, off, dis);
    k_B2<<<NBK, 256, 0, stream>>>(tmp, boff, off, dis, ssrcw);

    const int aggThreads = NN * 16;
    const int aggBlocks = aggThreads / TPB;   // exact: 6250
    float* nodeOut = out + NG;

    // conv1 aggregate: H1h = relu(agg(Ah)+b1) ; nodeOut partial 1
    k_agg<1><<<aggBlocks, TPB, 0, stream>>>(Ah, ssrcw, off, dis, b1, Wn, bn, W2h, H1h, nodeOut);

    // conv2 FUSED: M = agg(H1h); H2h = relu(M@W2+b2) ; nodeOut partial 2   (gemm2 deleted)
    k_agg<2><<<aggBlocks, TPB, 24832, stream>>>(H1h, ssrcw, off, dis, b2, Wn, bn, W2h, H2h, nodeOut);

    // pooling + graph head
    k_pool<<<NG, 768, 0, stream>>>(H1h, H2h, batch, Wg, bg, out);
}

// Round 21
// 237.780 us; speedup vs baseline: 1.0441x; 1.0441x over previous
//
#include <hip/hip_runtime.h>
#include <hip/hip_fp16.h>

#define NN 100000      // nodes
#define NE 1600000     // edges
#define INC 128        // in channels
#define HID 96         // hidden
#define NG 512         // graphs

#define GEMM1_BLOCKS 1563        // ceil(NN/64)
#define G2_BLOCKS 1563           // ceil(NN/64) for MFMA gemm2

#define BK_SHIFT 8
#define BK_SIZE 256
#define NBK 391                  // ceil(NN/256)
#define A_EPB 4096               // edges per A-pass block
#define A_BLOCKS 391             // ceil(NE/4096)

typedef _Float16 half8 __attribute__((ext_vector_type(8)));
typedef float f32x4 __attribute__((ext_vector_type(4)));

// ---------------- FUSED: A1 (per-block bucket histogram) ∥ W1+W2 frag pack ----------------
__global__ __launch_bounds__(256) void k_pack_a1(const int* __restrict__ dst,
                                                 int* __restrict__ histAB,
                                                 const float* __restrict__ W1,
                                                 const float* __restrict__ W2,
                                                 __half* __restrict__ W1frag,
                                                 __half* __restrict__ W2frag) {
    const int tid = threadIdx.x;
    if (blockIdx.x < A_BLOCKS) {
        __shared__ int cnt[NBK];
        int ab = blockIdx.x;
        for (int i = tid; i < NBK; i += 256) cnt[i] = 0;
        __syncthreads();
        int e0 = ab * A_EPB;
#pragma unroll 4
        for (int q = 0; q < A_EPB / 256; ++q) {
            int e = e0 + q * 256 + tid;
            if (e < NE) atomicAdd(&cnt[dst[e] >> BK_SHIFT], 1);
        }
        __syncthreads();
        for (int i = tid; i < NBK; i += 256) histAB[ab * NBK + i] = cnt[i];
        return;
    }
    int p = (blockIdx.x - A_BLOCKS) * 256 + tid;
    if (p < 1536) {
        int kc = p / 384;
        int rem = p - kc * 384;
        int ct = rem >> 6;
        int l = rem & 63;
#pragma unroll
        for (int i = 0; i < 8; ++i) {
            int k = kc * 32 + ((l >> 4) << 3) + i;
            int c = ct * 16 + (l & 15);
            W1frag[p * 8 + i] = __float2half(W1[k * HID + c]);
        }
    } else {
        int q = p - 1536;
        if (q >= 1152) return;
        int kc = q / 384;
        int rem = q - kc * 384;
        int ct = rem >> 6;
        int l = rem & 63;
#pragma unroll
        for (int i = 0; i < 8; ++i) {
            int k = kc * 32 + ((l >> 4) << 3) + i;
            int c = ct * 16 + (l & 15);
            W2frag[q * 8 + i] = __float2half(W2[k * HID + c]);
        }
    }
}

// ---------------- scanS: column prefix of histAB + bucket prefix -> boff ----------------
__global__ __launch_bounds__(512) void k_scanS(int* __restrict__ histAB, int* __restrict__ boff) {
    __shared__ int tot[512];
    int t = threadIdx.x;
    int run = 0;
    if (t < NBK) {
        for (int blk = 0; blk < A_BLOCKS; ++blk) {
            int idx = blk * NBK + t;
            int v = histAB[idx];
            histAB[idx] = run;
            run += v;
        }
    }
    tot[t] = (t < NBK) ? run : 0;
    __syncthreads();
    for (int ofs = 1; ofs < 512; ofs <<= 1) {
        int v = (t >= ofs) ? tot[t - ofs] : 0;
        __syncthreads();
        tot[t] += v;
        __syncthreads();
    }
    if (t == 0) boff[0] = 0;
    if (t < NBK) boff[t + 1] = tot[t];
}

// ---------------- FUSED: A3 (binned edge write) ∥ gemm1 (MFMA fp16) ----------------
__global__ __launch_bounds__(256) void k_gemm1_a3(
        const float* __restrict__ X, const __half* __restrict__ W1frag,
        __half* __restrict__ Yh,
        const int* __restrict__ src, const int* __restrict__ dst,
        const int* __restrict__ boff, const int* __restrict__ histAB,
        unsigned* __restrict__ tmp) {
    __shared__ __half w1s[12288];
    const int tid = threadIdx.x;

    if (blockIdx.x < A_BLOCKS) {
        int* base = (int*)w1s;
        int* lcnt = base + NBK;
        int ab = blockIdx.x;
        for (int i = tid; i < NBK; i += 256) {
            base[i] = boff[i] + histAB[ab * NBK + i];
            lcnt[i] = 0;
        }
        __syncthreads();
        int e0 = ab * A_EPB;
#pragma unroll 4
        for (int q = 0; q < A_EPB / 256; ++q) {
            int e = e0 + q * 256 + tid;
            if (e < NE) {
                int d = dst[e];
                int bk = d >> BK_SHIFT;
                int lp = atomicAdd(&lcnt[bk], 1);
                tmp[base[bk] + lp] = (unsigned)src[e] | ((unsigned)(d & (BK_SIZE - 1)) << 17);
            }
        }
        return;
    }

    // ---- gemm1 MFMA body (K = 128, 4 steps) ----
    {
        half8* d8 = (half8*)w1s;
        const half8* s8 = (const half8*)W1frag;
        for (int i = tid; i < 1536; i += 256) d8[i] = s8[i];
    }
    __syncthreads();
    const int w = tid >> 6;
    const int l = tid & 63;
    const int row0 = (blockIdx.x - A_BLOCKS) * 64 + w * 16;
    int arow = row0 + (l & 15);
    if (arow >= NN) arow = NN - 1;
    f32x4 acc[6] = {};
#pragma unroll
    for (int kc = 0; kc < 4; ++kc) {
        const float* xp = &X[(size_t)arow * INC + kc * 32 + ((l >> 4) << 3)];
        float4 xa = *(const float4*)xp;
        float4 xb = *(const float4*)(xp + 4);
        half8 a;
        a[0] = (_Float16)xa.x; a[1] = (_Float16)xa.y;
        a[2] = (_Float16)xa.z; a[3] = (_Float16)xa.w;
        a[4] = (_Float16)xb.x; a[5] = (_Float16)xb.y;
        a[6] = (_Float16)xb.z; a[7] = (_Float16)xb.w;
#pragma unroll
        for (int ct = 0; ct < 6; ++ct) {
            half8 b = *(const half8*)&w1s[((kc * 6 + ct) * 64 + l) * 8];
            acc[ct] = __builtin_amdgcn_mfma_f32_16x16x32_f16(a, b, acc[ct], 0, 0, 0);
        }
    }
    const int orow = row0 + ((l >> 4) << 2);
    const int col = l & 15;
#pragma unroll
    for (int ct = 0; ct < 6; ++ct)
#pragma unroll
        for (int i = 0; i < 4; ++i) {
            int r = orow + i;
            if (r < NN) Yh[(size_t)r * HID + ct * 16 + col] = __float2half(acc[ct][i]);
        }
}

// ---------------- B1: per-bucket degree count -> off (+dis); 1 node/thread ----------------
__global__ __launch_bounds__(256) void k_B1(const unsigned* __restrict__ tmp,
                                            const int* __restrict__ boff,
                                            int* __restrict__ off, float* __restrict__ dis) {
    __shared__ int cnt[BK_SIZE];
    __shared__ int psum[256];
    const int t = threadIdx.x;
    const int b = blockIdx.x;
    const int nb = b << BK_SHIFT;
    const int rbeg = boff[b], rend = boff[b + 1];
    cnt[t] = 0;
    __syncthreads();
    for (int e = rbeg + t; e < rend; e += 256) {
        unsigned u = tmp[e];
        atomicAdd(&cnt[u >> 17], 1);
    }
    __syncthreads();
    int c = cnt[t];
    psum[t] = c;
    __syncthreads();
    for (int ofs = 1; ofs < 256; ofs <<= 1) {
        int v = (t >= ofs) ? psum[t - ofs] : 0;
        __syncthreads();
        psum[t] += v;
        __syncthreads();
    }
    int node = nb + t;
    if (node < NN) {
        off[node] = rbeg + psum[t] - c;
        dis[node] = rsqrtf((float)(c + 1));
    }
    if (b == NBK - 1 && t == 0) off[NN] = rend;
}

// ---------------- B2: per-bucket scatter into final CSR {src, w} ----------------
__global__ __launch_bounds__(256) void k_B2(const unsigned* __restrict__ tmp,
                                            const int* __restrict__ boff,
                                            const int* __restrict__ off,
                                            const float* __restrict__ dis,
                                            int2* __restrict__ ssrcw) {
    __shared__ int cnt[BK_SIZE];
    const int t = threadIdx.x;
    const int b = blockIdx.x;
    const int nb = b << BK_SHIFT;
    const int rbeg = boff[b], rend = boff[b + 1];
    cnt[t] = 0;
    __syncthreads();
    for (int e = rbeg + t; e < rend; e += 256) {
        unsigned u = tmp[e];
        int s = (int)(u & 0x1FFFFu);
        int dl = (int)(u >> 17);
        int d = nb + dl;
        int pos = off[d] + atomicAdd(&cnt[dl], 1);
        float w = dis[s] * dis[d];
        ssrcw[pos] = make_int2(s, __float_as_int(w));
    }
}

// ---------------- GEMM2 (MFMA fp16, standalone; layout HW-validated round 10) ----------------
__global__ __launch_bounds__(256) void k_gemm2(const __half* __restrict__ Xh,
                                               const __half* __restrict__ W2frag,
                                               __half* __restrict__ Yh) {
    __shared__ __half w2s[9216];
    const int tid = threadIdx.x;
    {
        half8* d8 = (half8*)w2s;
        const half8* s8 = (const half8*)W2frag;
        for (int i = tid; i < 1152; i += 256) d8[i] = s8[i];
    }
    __syncthreads();
    const int w = tid >> 6;
    const int l = tid & 63;
    const int row0 = blockIdx.x * 64 + w * 16;
    int arow = row0 + (l & 15);
    if (arow >= NN) arow = NN - 1;
    f32x4 acc[6] = {};
#pragma unroll
    for (int kc = 0; kc < 3; ++kc) {
        half8 a = *(const half8*)&Xh[(size_t)arow * HID + kc * 32 + ((l >> 4) << 3)];
#pragma unroll
        for (int ct = 0; ct < 6; ++ct) {
            half8 b = *(const half8*)&w2s[((kc * 6 + ct) * 64 + l) * 8];
            acc[ct] = __builtin_amdgcn_mfma_f32_16x16x32_f16(a, b, acc[ct], 0, 0, 0);
        }
    }
    const int orow = row0 + ((l >> 4) << 2);
    const int col = l & 15;
#pragma unroll
    for (int ct = 0; ct < 6; ++ct)
#pragma unroll
        for (int i = 0; i < 4; ++i) {
            int r = orow + i;
            if (r < NN) Yh[(size_t)r * HID + ct * 16 + col] = __float2half(acc[ct][i]);
        }
}

// ---------------- agg batch helper: B edges, int2 descriptors ----------------
template <int B>
__device__ __forceinline__ void agg_batch(const __half* __restrict__ Ah,
                                          const int2* __restrict__ ssrcw, int j, int t,
                                          float& a0x, float& a0y, float& a1x, float& a1y,
                                          float& a2x, float& a2y) {
    int2 e[B];
#pragma unroll
    for (int q = 0; q < B; ++q) e[q] = ssrcw[j + q];
    float w[B];
    const __half2* ap[B];
#pragma unroll
    for (int q = 0; q < B; ++q) {
        w[q] = __int_as_float(e[q].y);
        ap[q] = (const __half2*)(Ah + (size_t)e[q].x * HID);
    }
    __half2 g0[B], g1[B], g2[B];
#pragma unroll
    for (int q = 0; q < B; ++q) {
        g0[q] = ap[q][t];
        g1[q] = ap[q][t + 16];
        g2[q] = ap[q][t + 32];
    }
#pragma unroll
    for (int q = 0; q < B; ++q) {
        float2 f0 = __half22float2(g0[q]);
        float2 f1 = __half22float2(g1[q]);
        float2 f2 = __half22float2(g2[q]);
        a0x += f0.x * w[q]; a0y += f0.y * w[q];
        a1x += f1.x * w[q]; a1y += f1.y * w[q];
        a2x += f2.x * w[q]; a2y += f2.y * w[q];
    }
}

// ---------------- fused GCN aggregation + node-logit partial (16 lanes/dst, half2) ------
template <int PHASE>
__global__ __launch_bounds__(256) void k_agg(const __half* __restrict__ Ah,
                                             const int2* __restrict__ ssrcw,
                                             const int* __restrict__ off,
                                             const float* __restrict__ dis,
                                             const float* __restrict__ bias,
                                             const float* __restrict__ Wn,
                                             const float* __restrict__ bn,
                                             __half* __restrict__ outh,
                                             float* __restrict__ nodeOut) {
    int gid = blockIdx.x * blockDim.x + threadIdx.x;
    int d = gid >> 4;
    int t = gid & 15;
    if (d >= NN) return;
    const int beg = off[d], end = off[d + 1];
    const float dd = dis[d];
    const __half2* ad2 = (const __half2*)(Ah + (size_t)d * HID);
    float2 s0 = __half22float2(ad2[t]);
    float2 s1 = __half22float2(ad2[t + 16]);
    float2 s2 = __half22float2(ad2[t + 32]);
    const float dd2 = dd * dd;
    float a0x = s0.x * dd2, a0y = s0.y * dd2;
    float a1x = s1.x * dd2, a1y = s1.y * dd2;
    float a2x = s2.x * dd2, a2y = s2.y * dd2;
    int j = beg;
    for (; j + 11 < end; j += 12)
        agg_batch<12>(Ah, ssrcw, j, t, a0x, a0y, a1x, a1y, a2x, a2y);
    for (; j + 3 < end; j += 4)
        agg_batch<4>(Ah, ssrcw, j, t, a0x, a0y, a1x, a1y, a2x, a2y);
    for (; j < end; ++j) {
        int2 e0 = ssrcw[j];
        float w0 = __int_as_float(e0.y);
        const __half2* a0 = (const __half2*)(Ah + (size_t)e0.x * HID);
        float2 f0 = __half22float2(a0[t]);
        float2 f1 = __half22float2(a0[t + 16]);
        float2 f2 = __half22float2(a0[t + 32]);
        a0x += f0.x * w0; a0y += f0.y * w0;
        a1x += f1.x * w0; a1y += f1.y * w0;
        a2x += f2.x * w0; a2y += f2.y * w0;
    }
    const float2* b2p = (const float2*)bias;
    float2 b0 = b2p[t], b1 = b2p[t + 16], b2 = b2p[t + 32];
    float h0x = fmaxf(a0x + b0.x, 0.f), h0y = fmaxf(a0y + b0.y, 0.f);
    float h1x = fmaxf(a1x + b1.x, 0.f), h1y = fmaxf(a1y + b1.y, 0.f);
    float h2x = fmaxf(a2x + b2.x, 0.f), h2y = fmaxf(a2y + b2.y, 0.f);
    __half2* o2 = (__half2*)(outh + (size_t)d * HID);
    o2[t]      = __floats2half2_rn(h0x, h0y);
    o2[t + 16] = __floats2half2_rn(h1x, h1y);
    o2[t + 32] = __floats2half2_rn(h2x, h2y);

    const int woff = (PHASE == 1) ? 0 : 96;
    const float2* wn2 = (const float2*)(Wn + woff);
    float2 w0v = wn2[t], w1v = wn2[t + 16], w2v = wn2[t + 32];
    float partial = h0x * w0v.x + h0y * w0v.y + h1x * w1v.x + h1y * w1v.y +
                    h2x * w2v.x + h2y * w2v.y;
#pragma unroll
    for (int m = 8; m; m >>= 1) partial += __shfl_down(partial, m, 16);
    if (t == 0) {
        if (PHASE == 1) nodeOut[d] = partial + bn[0];
        else            nodeOut[d] += partial;
    }
}

// ---------------- graph pooling + graph head (fp16 H inputs, 2x node unroll) ----------------
__global__ __launch_bounds__(768) void k_pool(const __half* __restrict__ h1,
                                              const __half* __restrict__ h2,
                                              const int* __restrict__ batch,
                                              const float* __restrict__ Wg,
                                              const float* __restrict__ bg,
                                              float* __restrict__ out) {
    int g = blockIdx.x;
    int tid = threadIdx.x;       // 0..767
    int way = tid / 192;         // 0..3
    int f = tid - way * 192;     // 0..191

    int lo = 0, hi = NN;
    while (lo < hi) { int mid = (lo + hi) >> 1; if (batch[mid] < g) lo = mid + 1; else hi = mid; }
    int start = lo;
    hi = NN;
    while (lo < hi) { int mid = (lo + hi) >> 1; if (batch[mid] < g + 1) lo = mid + 1; else hi = mid; }
    int end = lo;

    const __half* hsrc = (f < HID) ? h1 : h2;
    int ff = (f < HID) ? f : f - HID;
    float sum = 0.f, mx = 0.f;  // h >= 0 post-relu
    int n = start + way;
    for (; n + 4 < end; n += 8) {
        float v0 = __half2float(hsrc[(size_t)n * HID + ff]);
        float v1 = __half2float(hsrc[(size_t)(n + 4) * HID + ff]);
        sum += v0 + v1;
        mx = fmaxf(mx, fmaxf(v0, v1));
    }
    if (n < end) {
        float v0 = __half2float(hsrc[(size_t)n * HID + ff]);
        sum += v0;
        mx = fmaxf(mx, v0);
    }
    __shared__ float rsum[4][192];
    __shared__ float rmax[4][192];
    rsum[way][f] = sum;
    rmax[way][f] = mx;
    __syncthreads();
    if (way == 0) {
        sum = rsum[0][f] + rsum[1][f] + rsum[2][f] + rsum[3][f];
        mx = fmaxf(fmaxf(rmax[0][f], rmax[1][f]), fmaxf(rmax[2][f], rmax[3][f]));
        float cnt = (float)(end - start);
        float mean = sum / fmaxf(cnt, 1.0f);
        rsum[0][f] = mean * Wg[f] + mx * Wg[192 + f];
    }
    __syncthreads();
    if (tid < 64) {
        float acc = rsum[0][tid] + rsum[0][tid + 64] + rsum[0][tid + 128];
#pragma unroll
        for (int m = 32; m; m >>= 1) acc += __shfl_down(acc, m, 64);
        if (tid == 0) out[g] = acc + bg[0];
    }
}

extern "C" void kernel_launch(void* const* d_in, const int* in_sizes, int n_in,
                              void* d_out, int out_size, void* d_ws, size_t ws_size,
                              hipStream_t stream) {
    const float* x    = (const float*)d_in[0];
    const int*   ei   = (const int*)d_in[1];
    const int*   srcp = ei;
    const int*   dstp = ei + NE;
    const int*   batch = (const int*)d_in[2];
    const float* W1 = (const float*)d_in[3];
    const float* b1 = (const float*)d_in[4];
    const float* W2 = (const float*)d_in[5];
    const float* b2 = (const float*)d_in[6];
    const float* Wn = (const float*)d_in[7];
    const float* bn = (const float*)d_in[8];
    const float* Wg = (const float*)d_in[9];
    const float* bg = (const float*)d_in[10];
    float* out = (float*)d_out;

    char* p = (char*)d_ws;
    auto alloc = [&](size_t bytes) {
        char* r = p;
        p += (bytes + 255) & ~(size_t)255;
        return (void*)r;
    };
    float*    dis    = (float*)alloc(NN * 4);
    int*      off    = (int*)alloc((NN + 1) * 4);
    int*      boff   = (int*)alloc((NBK + 1) * 4);
    int*      histAB = (int*)alloc((size_t)A_BLOCKS * NBK * 4);
    unsigned* tmp    = (unsigned*)alloc((size_t)NE * 4);
    int2*     ssrcw  = (int2*)alloc((size_t)NE * 8);
    __half*   Ah     = (__half*)alloc((size_t)NN * HID * 2);   // hw buffer (both convs)
    __half*   H1h    = (__half*)alloc((size_t)NN * HID * 2);
    __half*   H2h    = (__half*)alloc((size_t)NN * HID * 2);
    __half*   W1frag = (__half*)alloc(12288 * 2);
    __half*   W2frag = (__half*)alloc(9216 * 2);

    const int TPB = 256;

    // CSR build + weight pack: [A1 ∥ pack] ; scanS ; [A3 ∥ gemm1-MFMA] ; B1 ; B2
    k_pack_a1<<<A_BLOCKS + 11, TPB, 0, stream>>>(dstp, histAB, W1, W2, W1frag, W2frag);
    k_scanS<<<1, 512, 0, stream>>>(histAB, boff);
    k_gemm1_a3<<<A_BLOCKS + GEMM1_BLOCKS, 256, 0, stream>>>(
        x, W1frag, Ah, srcp, dstp, boff, histAB, tmp);
    k_B1<<<NBK, 256, 0, stream>>>(tmp, boff, off, dis);
    k_B2<<<NBK, 256, 0, stream>>>(tmp, boff, off, dis, ssrcw);

    const int aggThreads = NN * 16;
    float* nodeOut = out + NG;

    // conv1 aggregate (16-lane half2): H1h ; nodeOut partial 1
    k_agg<1><<<(aggThreads + TPB - 1) / TPB, TPB, 0, stream>>>(Ah, ssrcw, off, dis, b1, Wn, bn, H1h, nodeOut);

    // conv2 transform (MFMA, standalone)
    k_gemm2<<<G2_BLOCKS, 256, 0, stream>>>(H1h, W2frag, Ah);

    // conv2 aggregate: H2h ; nodeOut partial 2
    k_agg<2><<<(aggThreads + TPB - 1) / TPB, TPB, 0, stream>>>(Ah, ssrcw, off, dis, b2, Wn, bn, H2h, nodeOut);

    // pooling + graph head
    k_pool<<<NG, 768, 0, stream>>>(H1h, H2h, batch, Wg, bg, out);
}